// Round 1
// 490.610 us; speedup vs baseline: 1.0350x; 1.0350x over previous
//
#include <hip/hip_runtime.h>
#include <hip/hip_bf16.h>
#include <cstdint>
#include <cstddef>

typedef unsigned short u16;
typedef unsigned int   u32;
typedef short bf16x8 __attribute__((ext_vector_type(8)));   // 8 bf16 = 4 VGPRs
typedef float f32x4  __attribute__((ext_vector_type(4)));

__device__ __forceinline__ float bf2f(u16 v){ return __uint_as_float(((u32)v)<<16); }
__device__ __forceinline__ u16 f2bf(float f){
  u32 x = __float_as_uint(f);
  return (u16)((x + 0x7FFFu + ((x>>16)&1u)) >> 16);   // round-to-nearest-even
}
__device__ __forceinline__ void atomAddF(float* p, float v){ unsafeAtomicAdd(p, v); }

// ---------------- zero helper ----------------
__global__ void kzero(int* p, int n){
  int i = blockIdx.x*blockDim.x + threadIdx.x;
  if(i < n) p[i] = 0;
}

// ---------------- per-side degree counts ----------------
__global__ void kdeg2(const int* __restrict__ ei0, const int* __restrict__ ei1,
                      int* __restrict__ deg0, int* __restrict__ deg1, int E){
  int e = blockIdx.x*blockDim.x + threadIdx.x;
  if(e >= E) return;
  atomicAdd(&deg0[ei0[e]], 1);
  atomicAdd(&deg1[ei1[e]], 1);
}

// ---------------- hierarchical exclusive scan (3 phases) ----------------
__global__ __launch_bounds__(256) void ktilesum(const int* __restrict__ deg0,
                                                const int* __restrict__ deg1,
                                                int* __restrict__ tsum,
                                                int N, int nt){
  __shared__ int sh[256];
  const int b = blockIdx.x;
  const int* deg = (b < nt) ? deg0 : deg1;
  const int tile = (b < nt) ? b : b - nt;
  const int t = threadIdx.x;
  const int i = tile*256 + t;
  sh[t] = (i < N) ? deg[i] : 0;
  __syncthreads();
  for(int s = 128; s > 0; s >>= 1){
    if(t < s) sh[t] += sh[t+s];
    __syncthreads();
  }
  if(t == 0) tsum[b] = sh[0];
}
__global__ __launch_bounds__(256) void kmid(int* __restrict__ tsum,
                                            int* __restrict__ off0,
                                            int* __restrict__ off1,
                                            int N, int nt){
  __shared__ int sh[256];
  const int b = blockIdx.x;
  int* ts = tsum + b*nt;
  const int t = threadIdx.x;
  sh[t] = (t < nt) ? ts[t] : 0;
  __syncthreads();
  for(int s = 1; s < 256; s <<= 1){
    int x = (t >= s) ? sh[t-s] : 0;
    __syncthreads();
    sh[t] += x;
    __syncthreads();
  }
  if(t < nt) ts[t] = (t == 0) ? 0 : sh[t-1];
  if(t == 255){ int* off = b ? off1 : off0; off[N] = sh[255]; }
}
// phase 3: intra-tile scan + tile base -> off[]; blocks b<nt also emit dinv
__global__ __launch_bounds__(256) void kapply(const int* __restrict__ deg0,
                                              const int* __restrict__ deg1,
                                              const int* __restrict__ tsum,
                                              int* __restrict__ off0,
                                              int* __restrict__ off1,
                                              float* __restrict__ dinv,
                                              int N, int nt){
  __shared__ int sh[256];
  const int b = blockIdx.x;
  const int* deg = (b < nt) ? deg0 : deg1;
  int*       off = (b < nt) ? off0 : off1;
  const int tile = (b < nt) ? b : b - nt;
  const int base = tsum[b];
  const int t = threadIdx.x;
  const int i = tile*256 + t;
  sh[t] = (i < N) ? deg[i] : 0;
  __syncthreads();
  for(int s = 1; s < 256; s <<= 1){
    int x = (t >= s) ? sh[t-s] : 0;
    __syncthreads();
    sh[t] += x;
    __syncthreads();
  }
  if(i < N){
    off[i] = base + ((t == 0) ? 0 : sh[t-1]);
    if(b < nt){
      int d = deg0[i] + deg1[i];
      dinv[i] = (d > 1) ? (1.f/(float)d) : 0.f;   // deg==1 hyperedges dropped
    }
  }
}

// ---------------- counting-sort + per-edge SoA descriptors ----------------
// euv[pos]  = u | (v<<16)         (N < 65536)
// coef[pos] = (rc, iu*rc, iv*rc, ie)
// ebat[pos] = batch id (< 256)
__global__ void kperm(const int* __restrict__ ei0, const int* __restrict__ ei1,
                      const float* __restrict__ nimp, const float* __restrict__ dinv,
                      const int* __restrict__ batch, const int* __restrict__ off0,
                      int* __restrict__ cur0, u32* __restrict__ euv,
                      f32x4* __restrict__ coef, unsigned char* __restrict__ ebat,
                      int* __restrict__ orig, float* __restrict__ imp, int E){
  int e = blockIdx.x*blockDim.x + threadIdx.x;
  if(e >= E) return;
  int u = ei0[e], v = ei1[e];
  int pos = off0[u] + atomicAdd(&cur0[u], 1);
  float iu = dinv[u], iv = dinv[v];
  float rc = (iu > 0.f && iv > 0.f) ? (1.f/3.f)
           : ((iu > 0.f || iv > 0.f) ? 0.5f : 1.f);
  float ie = fminf(nimp[u], nimp[v]);
  euv[pos]  = (u32)u | ((u32)v << 16);
  f32x4 c; c.x = rc; c.y = iu*rc; c.z = iv*rc; c.w = ie;
  coef[pos] = c;
  ebat[pos] = (unsigned char)batch[u];
  orig[pos] = e;
  imp[pos]  = ie;
}

// ---------------- v-side incidence list (sorted edge ids) ----------------
__global__ void kfillv(const u32* __restrict__ euv, const int* __restrict__ off1,
                       int* __restrict__ cur1, int* __restrict__ list1, int E){
  int p = blockIdx.x*blockDim.x + threadIdx.x;
  if(p >= E) return;
  int v = (int)(euv[p] >> 16);
  list1[off1[v] + atomicAdd(&cur1[v], 1)] = p;
}

// ---------------- W -> fragment-ready layout (all 3 layers, one launch) -------
__global__ void kprepw(const float* __restrict__ W0, u16* __restrict__ wf0,
                       const float* __restrict__ W1, u16* __restrict__ wf1,
                       const float* __restrict__ W2, u16* __restrict__ wf2){
  const int b = blockIdx.x;
  const float* W; u16* wf; int NC, sbase;
  if(b == 0){ W = W0; wf = wf0; NC = 1; sbase = 0; }
  else if(b <= 2){ W = W1; wf = wf1; NC = 2; sbase = (b-1)*256; }
  else { W = W2; wf = wf2; NC = 2; sbase = (b-3)*256; }
  int s = sbase + threadIdx.x;
  if(s >= 4*NC*64) return;
  int lane = s & 63;
  int c    = (s >> 6) % NC;
  int tt   = s / (NC*64);
  int n  = tt*16 + (lane & 15);
  int k0 = c*32 + (lane >> 4)*8;
  #pragma unroll
  for(int j = 0; j < 8; j++)
    wf[(size_t)s*8 + j] = f2bf(W[(size_t)(k0 + j)*64 + n]);
}

// ---------------- layer 0: MFMA GEMM (edge_attr[orig]*imp @ W0) ---------------
__global__ __launch_bounds__(256) void kgemm0(const float* __restrict__ srcf,
                                              u16* __restrict__ buf,
                                              const u16* __restrict__ wf,
                                              const float* __restrict__ imp,
                                              const int* __restrict__ orig,
                                              int E){
  const int t    = threadIdx.x;
  const int wv   = t >> 6;
  const int lane = t & 63;
  const int quad = lane >> 4;
  const int l15  = lane & 15;
  const int row0 = blockIdx.x*64 + wv*16;
  if(row0 >= E) return;                      // E % 16 == 0

  bf16x8 bfr[4];
  #pragma unroll
  for(int i = 0; i < 4; i++)
    bfr[i] = *(const bf16x8*)(wf + ((size_t)i*64 + lane)*8);

  const int myrow = row0 + l15;
  const int oe = orig[myrow];
  const float* s = srcf + (size_t)oe*32 + quad*8;
  const float sc = imp[myrow];
  f32x4 v0 = *(const f32x4*)s;
  f32x4 v1 = *(const f32x4*)(s+4);
  bf16x8 afr;
  afr[0]=(short)f2bf(v0.x*sc); afr[1]=(short)f2bf(v0.y*sc);
  afr[2]=(short)f2bf(v0.z*sc); afr[3]=(short)f2bf(v0.w*sc);
  afr[4]=(short)f2bf(v1.x*sc); afr[5]=(short)f2bf(v1.y*sc);
  afr[6]=(short)f2bf(v1.z*sc); afr[7]=(short)f2bf(v1.w*sc);

  #pragma unroll
  for(int tt = 0; tt < 4; tt++){
    f32x4 a = {0.f,0.f,0.f,0.f};
    a = __builtin_amdgcn_mfma_f32_16x16x32_bf16(afr, bfr[tt], a, 0, 0, 0);
    const int n = tt*16 + l15;
    #pragma unroll
    for(int r = 0; r < 4; r++)
      buf[(size_t)(row0 + quad*4 + r)*64 + n] = f2bf(a[r]);
  }
}

// ---------------- aggregate: 8 rows per wave-instr, col-block layout ----------
// lane = (rsub = lane>>3 row-in-group, cb = lane&7 col-block of 8 cols)
__global__ __launch_bounds__(256) void kagg(const u16* __restrict__ buf,
                                            const int* __restrict__ off0,
                                            const int* __restrict__ off1,
                                            const int* __restrict__ list1,
                                            u16* __restrict__ heb, int N){
  const int t = threadIdx.x, wv = t >> 6, lane = t & 63;
  const int n = blockIdx.x*4 + wv;
  if(n >= N) return;
  const int rsub = lane >> 3, cb = lane & 7;
  float acc[8];
  #pragma unroll
  for(int k = 0; k < 8; k++) acc[k] = 0.f;

  auto accum = [&](uint4 x){
    acc[0] += bf2f((u16)x.x); acc[1] += bf2f((u16)(x.x>>16));
    acc[2] += bf2f((u16)x.y); acc[3] += bf2f((u16)(x.y>>16));
    acc[4] += bf2f((u16)x.z); acc[5] += bf2f((u16)(x.z>>16));
    acc[6] += bf2f((u16)x.w); acc[7] += bf2f((u16)(x.w>>16));
  };
  const uint4 zero4 = {0,0,0,0};

  // u-side: contiguous rows [off0[n], off0[n+1])
  {
    const int s0 = off0[n], d0 = off0[n+1] - s0;
    const u16* base = buf + (size_t)s0*64;
    int j = 0;
    for(; j + 8 <= d0; j += 8)
      accum(*(const uint4*)(base + (size_t)(j+rsub)*64 + cb*8));
    if(j < d0)
      accum((rsub < d0-j) ? *(const uint4*)(base + (size_t)(j+rsub)*64 + cb*8) : zero4);
  }
  // v-side: random rows via list1
  {
    const int s1 = off1[n], d1 = off1[n+1] - s1;
    int j = 0;
    for(; j + 8 <= d1; j += 8){
      int e = list1[s1 + j + rsub];
      accum(*(const uint4*)(buf + (size_t)e*64 + cb*8));
    }
    if(j < d1){
      uint4 x = zero4;
      if(rsub < d1-j){
        int e = list1[s1 + j + rsub];
        x = *(const uint4*)(buf + (size_t)e*64 + cb*8);
      }
      accum(x);
    }
  }
  // reduce across rsub (lanes differing in bits 3..5)
  #pragma unroll
  for(int m = 8; m <= 32; m <<= 1)
    #pragma unroll
    for(int k = 0; k < 8; k++) acc[k] += __shfl_xor(acc[k], m);
  // write: rsub==0 lanes store 8 cols (16 B)
  if(rsub == 0){
    u32 o[4];
    #pragma unroll
    for(int k = 0; k < 4; k++)
      o[k] = (u32)f2bf(acc[2*k]) | ((u32)f2bf(acc[2*k+1]) << 16);
    *(uint4*)(heb + (size_t)n*64 + cb*8) = make_uint4(o[0],o[1],o[2],o[3]);
  }
}

// ---------------- fused: gather + epilogue + register-pool (+ GEMM) ------------
// Restructured for latency hiding:
//  - SoA descriptors staged lane-parallel (6 VGPRs for 16 edges), broadcast via shfl
//  - all 48 gathers of a 16-edge iteration issued before consumption
//  - next iteration's descriptors prefetched before the epilogue
//  - __launch_bounds__(256,3): allow ~170 VGPRs (4 waves/SIMD at ~120 actual)
template<bool DO_GEMM>
__global__ __launch_bounds__(256, 3) void kfused(u16* buf,               // r/w
                                                 const u16* __restrict__ heb,
                                                 const u32* __restrict__ euv,
                                                 const f32x4* __restrict__ coef,
                                                 const unsigned char* __restrict__ ebat,
                                                 const float* __restrict__ bias,
                                                 const u16* __restrict__ wf,
                                                 float* __restrict__ ghL,  // gh + layer*64
                                                 int E){
  constexpr int HTSZ = DO_GEMM ? 4*16*72 : 4;       // 16 rows x 72 per wave
  __shared__ __align__(16) u16 hT[HTSZ];
  const int t = threadIdx.x, wv = t >> 6, lane = t & 63;
  const int quad = lane >> 4, l15 = lane & 15;
  const float bd = bias[lane];

  bf16x8 bfr[8];
  if(DO_GEMM){
    #pragma unroll
    for(int i = 0; i < 8; i++)
      bfr[i] = *(const bf16x8*)(wf + ((size_t)i*64 + lane)*8);
  }

  float pool = 0.f;
  int cur_g = -1;
  const int base = blockIdx.x*256 + wv*64;   // wave owns 64 contiguous edges

  // descriptor bank for iteration 0 (lane l15 holds edge base+l15)
  u32 uvp = 0; f32x4 cf = {0.f,0.f,0.f,0.f}; int bt = 0;
  if(base < E){                              // E % 16 == 0 -> base+15 < E
    uvp = euv[base + l15];
    cf  = coef[base + l15];
    bt  = (int)ebat[base + l15];
  }

  #pragma unroll
  for(int it = 0; it < 4; it++){
    const int r0 = base + it*16;
    if(r0 < E){
      // ---- issue all 48 gathers for these 16 edges ----
      u16 bvr[16], hur[16], hvr[16];
      #pragma unroll
      for(int q = 0; q < 16; q++){
        const u32 uv = (u32)__shfl((int)uvp, q);
        const int uq = (int)(uv & 0xffffu);
        const int vq = (int)(uv >> 16);
        hvr[q] = heb[(size_t)vq*64 + lane];
        hur[q] = heb[(size_t)uq*64 + lane];
        bvr[q] = buf[(size_t)(r0 + q)*64 + lane];
      }
      // ---- prefetch next iteration's descriptors ----
      u32 uvpN = uvp; f32x4 cfN = cf; int btN = bt;
      if(it < 3){
        const int e1 = r0 + 16;
        if(e1 < E){
          uvpN = euv[e1 + l15];
          cfN  = coef[e1 + l15];
          btN  = (int)ebat[e1 + l15];
        }
      }
      // ---- epilogue: consume gathers as they land ----
      #pragma unroll
      for(int q = 0; q < 16; q++){
        const float rc   = __shfl(cf.x, q);
        const float iurc = __shfl(cf.y, q);
        const float ivrc = __shfl(cf.z, q);
        const float ie   = __shfl(cf.w, q);
        const int   bq   = __shfl(bt, q);
        float o = fmaxf(fmaf(bf2f(bvr[q]), rc,
                        fmaf(bf2f(hur[q]), iurc,
                        fmaf(bf2f(hvr[q]), ivrc, bd))), 0.f) * ie;
        if(bq != cur_g){                        // wave-uniform branch
          if(cur_g >= 0) atomAddF(&ghL[cur_g*192 + lane], pool);
          pool = 0.f;
          cur_g = bq;
        }
        pool += o;
        if(DO_GEMM) hT[wv*1152 + q*72 + lane] = f2bf(o);
      }
      uvp = uvpN; cf = cfN; bt = btN;
      // ---- stage 2: MFMA these 16 rows (wave-local LDS, no barrier) ----
      if(DO_GEMM){
        bf16x8 afr0 = *(const bf16x8*)&hT[wv*1152 + l15*72 + quad*8];
        bf16x8 afr1 = *(const bf16x8*)&hT[wv*1152 + l15*72 + 32 + quad*8];
        #pragma unroll
        for(int tt = 0; tt < 4; tt++){
          f32x4 a = {0.f,0.f,0.f,0.f};
          a = __builtin_amdgcn_mfma_f32_16x16x32_bf16(afr0, bfr[tt*2+0], a, 0, 0, 0);
          a = __builtin_amdgcn_mfma_f32_16x16x32_bf16(afr1, bfr[tt*2+1], a, 0, 0, 0);
          const int n = tt*16 + l15;
          #pragma unroll
          for(int r = 0; r < 4; r++)
            buf[(size_t)(r0 + quad*4 + r)*64 + n] = f2bf(a[r]);
        }
      }
    }
  }
  if(cur_g >= 0) atomAddF(&ghL[cur_g*192 + lane], pool);
}

__global__ void kfinal(const float* __restrict__ gh, float* __restrict__ out, int n){
  int i = blockIdx.x*blockDim.x + threadIdx.x;
  if(i < n) out[i] = gh[i];   // reference output dtype = float32
}

// ---------------- host ----------------
extern "C" void kernel_launch(void* const* d_in, const int* in_sizes, int n_in,
                              void* d_out, int out_size, void* d_ws, size_t ws_size,
                              hipStream_t stream) {
  const float* edge_attr = (const float*)d_in[1];
  const int*   ei        = (const int*)d_in[2];
  const int*   batch     = (const int*)d_in[3];
  const float* nimp      = (const float*)d_in[4];
  const float* Ws[3] = { (const float*)d_in[5], (const float*)d_in[7], (const float*)d_in[9] };
  const float* bs[3] = { (const float*)d_in[6], (const float*)d_in[8], (const float*)d_in[10] };

  const int E = in_sizes[1] / 32;   // edge_attr is (E, 32)
  const int N = in_sizes[4];        // node_imp is (N,)
  const int* ei0 = ei;
  const int* ei1 = ei + E;

  char* p = (char*)d_ws;
  auto carve = [&](size_t bytes)->char*{
    char* r = p; p += (bytes + 255) & ~(size_t)255; return r;
  };
  const int nt = (N + 255)/256;
  float* imp   = (float*)carve((size_t)E*4);
  int*   deg0  = (int*)  carve((size_t)4*N*4);       // deg0|deg1|cur0|cur1
  int*   deg1  = deg0 + N;
  int*   cur0  = deg0 + 2*N;
  int*   cur1  = deg0 + 3*N;
  float* dinv  = (float*)carve((size_t)N*4);
  int*   off0  = (int*)  carve((size_t)(N+1)*4);
  int*   off1  = (int*)  carve((size_t)(N+1)*4);
  int*   tsum  = (int*)  carve((size_t)2*nt*4);
  int*   orig  = (int*)  carve((size_t)E*4);
  int*   list1 = (int*)  carve((size_t)E*4);
  u32*   euv   = (u32*)  carve((size_t)E*4);
  f32x4* coef  = (f32x4*)carve((size_t)E*16);
  unsigned char* ebat = (unsigned char*)carve((size_t)E);
  u16*   heb   = (u16*)  carve((size_t)N*64*2);
  u16*   buf   = (u16*)  carve((size_t)E*64*2);      // xw / h' in-place
  float* gh    = (float*)carve((size_t)64*192*4);
  u16*   wfs[3];
  for(int l = 0; l < 3; l++) wfs[l] = (u16*)carve((size_t)4096*2);

  kzero<<<(4*N+255)/256, 256, 0, stream>>>(deg0, 4*N);
  kzero<<<(12288+255)/256, 256, 0, stream>>>((int*)gh, 12288);
  kdeg2<<<(E+255)/256, 256, 0, stream>>>(ei0, ei1, deg0, deg1, E);
  ktilesum<<<2*nt, 256, 0, stream>>>(deg0, deg1, tsum, N, nt);
  kmid<<<2, 256, 0, stream>>>(tsum, off0, off1, N, nt);
  kapply<<<2*nt, 256, 0, stream>>>(deg0, deg1, tsum, off0, off1, dinv, N, nt);
  kperm<<<(E+255)/256, 256, 0, stream>>>(ei0, ei1, nimp, dinv, batch, off0, cur0,
                                         euv, coef, ebat, orig, imp, E);
  kfillv<<<(E+255)/256, 256, 0, stream>>>(euv, off1, cur1, list1, E);
  kprepw<<<5, 256, 0, stream>>>(Ws[0], wfs[0], Ws[1], wfs[1], Ws[2], wfs[2]);

  const int nbG = (E + 63)/64;
  const int nbA = (N + 3)/4;
  const int nbF = (E + 255)/256;   // contiguous 256-edge chunk per block

  kgemm0<<<nbG, 256, 0, stream>>>(edge_attr, buf, wfs[0], imp, orig, E);
  kagg<<<nbA, 256, 0, stream>>>(buf, off0, off1, list1, heb, N);
  kfused<true ><<<nbF, 256, 0, stream>>>(buf, heb, euv, coef, ebat, bs[0], wfs[1], gh + 0*64, E);
  kagg<<<nbA, 256, 0, stream>>>(buf, off0, off1, list1, heb, N);
  kfused<true ><<<nbF, 256, 0, stream>>>(buf, heb, euv, coef, ebat, bs[1], wfs[2], gh + 1*64, E);
  kagg<<<nbA, 256, 0, stream>>>(buf, off0, off1, list1, heb, N);
  kfused<false><<<nbF, 256, 0, stream>>>(buf, heb, euv, coef, ebat, bs[2], nullptr, gh + 2*64, E);
  kfinal<<<(12288+255)/256, 256, 0, stream>>>(gh, (float*)d_out, 12288);
}